// Round 12
// baseline (248.527 us; speedup 1.0000x reference)
//
#include <hip/hip_runtime.h>

typedef unsigned short u16;
typedef short bf16x8 __attribute__((ext_vector_type(8)));
typedef float f32x4 __attribute__((ext_vector_type(4)));
typedef const __attribute__((address_space(1))) void* gptr_t;
typedef __attribute__((address_space(3))) void* lptr_t;

#define B_   64
#define N_   393
#define C_   768
#define H_   12
#define HD_  64
#define P_   197
#define BIAS_N 416
#define PPAD 208
#define VTP  448
#define M_KV (B_ * N_)   // 25152
#define M_PR (B_ * P_)   // 12608
#define SCALE_L2E 0.180336879f   // 0.125 * log2(e)

__device__ __forceinline__ u16 f2bf(float f) {
    unsigned u = __float_as_uint(f);
    return (u16)((u + 0x7FFFu + ((u >> 16) & 1u)) >> 16);
}
__device__ __forceinline__ unsigned cvt_pk_bf16(float lo, float hi) {
    unsigned r;
    asm("v_cvt_pk_bf16_f32 %0, %1, %2" : "=v"(r) : "v"(lo), "v"(hi));
    return r;
}
__device__ __forceinline__ float exp2_fast(float x) {
    float r;
    asm("v_exp_f32 %0, %1" : "=v"(r) : "v"(x));
    return r;
}

// ---------------------------------------------------------------------------
// conv_all: fused fp32->bf16 for x, wk, wv, proj_w (one launch)
// ---------------------------------------------------------------------------
__global__ __launch_bounds__(256) void conv_all(
    const float* __restrict__ x, const float* __restrict__ wk,
    const float* __restrict__ wv, const float* __restrict__ pw,
    u16* __restrict__ xh, u16* __restrict__ wkvh, u16* __restrict__ pwh)
{
    const int XN4 = 19316736 / 4;
    const int WN4 = 589824 / 4;
    int i = blockIdx.x * 256 + threadIdx.x;
    const float* src; u16* dst; int off;
    if (i < XN4) { src = x; dst = xh; off = i; }
    else {
        int j = i - XN4;
        int sec = j / WN4;
        off = j - sec * WN4;
        src = sec == 0 ? wk : (sec == 1 ? wv : pw);
        dst = sec == 0 ? wkvh : (sec == 1 ? wkvh + 589824 : pwh);
    }
    float4 v = ((const float4*)src)[off];
    u16 o[4] = {f2bf(v.x), f2bf(v.y), f2bf(v.z), f2bf(v.w)};
    *(uint2*)(dst + off * 4) = *(uint2*)o;
}

// ---------------------------------------------------------------------------
// prep1: q = q_learned + pos_embed -> qh (bf16 [P][C]); lk[h][p][8] fp32
// ---------------------------------------------------------------------------
__global__ __launch_bounds__(256) void prep1_kernel(
    const float* __restrict__ q_learned, const float* __restrict__ pos_embed,
    const float* __restrict__ rpe_w, u16* __restrict__ qh, float* __restrict__ lk)
{
    __shared__ float q_s[C_];
    const int p = blockIdx.x, t = threadIdx.x;
    for (int c = t; c < C_; c += 256) {
        float v = q_learned[c] + pos_embed[p * C_ + c];
        q_s[c] = v;
        qh[p * C_ + c] = f2bf(v);
    }
    __syncthreads();
    if (t < H_ * 8) {
        int h = t >> 3, u = t & 7;
        float s = 0.f;
        #pragma unroll 8
        for (int d = 0; d < HD_; ++d)
            s = fmaf(q_s[h * HD_ + d], rpe_w[d * 8 + u], s);
        lk[(h * P_ + p) * 8 + u] = s;
    }
}

// ---------------------------------------------------------------------------
// prep2: biasT[h][j][p] = lk[h][p][bucket] * log2(e)   (pre-scaled for exp2)
// ---------------------------------------------------------------------------
__global__ __launch_bounds__(256) void prep2_kernel(
    const float* __restrict__ lk, const int* __restrict__ rp_bucket,
    float* __restrict__ biasT)
{
    int bx = blockIdx.x;
    int h = bx / N_, j = bx % N_;
    int t = threadIdx.x;
    if (t >= PPAD) return;
    int jm;
    if (j == 0) jm = 0;
    else { jm = j - 1; if (jm >= 196) jm -= 196; jm += 1; }
    float v = 0.f;
    if (t < P_) {
        int bucket = rp_bucket[t * P_ + jm];
        v = lk[(h * P_ + t) * 8 + bucket] * 1.44269504f;
    }
    biasT[((size_t)h * BIAS_N + j) * PPAD + t] = v;
}

// ---------------------------------------------------------------------------
// Templated 128x128x64 bf16 MFMA GEMM with T4 counted-vmcnt pipeline:
// 2-deep tile staging (LDS 64KB, 2 blocks/CU), raw s_barrier + vmcnt(8) —
// NO vmcnt(0) drain in the main loop. Ledger: iter ks = {vmcnt(8): tile ks
// landed; bar; ds_read buf[ks&1]; lgkm(0); bar: all reads done; stage ks+2
// into buf[ks&1] (WAR safe, no reader until iter ks+2 post-vmcnt); MFMA}.
// Epilogue: iter10 no stage, iter11 vmcnt(0). XCD-bijective grid swizzle.
// ---------------------------------------------------------------------------
template <bool F32OUT>
__global__ __launch_bounds__(256, 2) void gemm_bf16(
    const u16* __restrict__ A, const u16* __restrict__ Bw,
    u16* __restrict__ Cb, float* __restrict__ Cf, const float* __restrict__ bias,
    int M, int ldc)
{
    __shared__ __align__(16) u16 As[2][8192];
    __shared__ __align__(16) u16 Bs[2][8192];

    const int gx = gridDim.x;
    const int nwg = gx * gridDim.y;
    const int orig = blockIdx.y * gx + blockIdx.x;
    const int xcd = orig & 7, rank = orig >> 3;
    const int q = nwg >> 3, r = nwg & 7;
    const int wgid = (xcd < r ? xcd * (q + 1) : r * (q + 1) + (xcd - r) * q) + rank;
    const int n0 = (wgid % gx) * 128;
    const int m0 = (wgid / gx) * 128;

    const int t = threadIdx.x;
    const int w = t >> 6, l = t & 63;
    const int wr = w >> 1, wc = w & 1;
    const int l15 = l & 15, lg = l >> 4;
    const int lrow = l >> 3, lslot = l & 7;
    const int Mc = M - 1;

    // staging source bases (k-offset added per tile)
    const u16* gA[4]; const u16* gB[4];
    #pragma unroll
    for (int i = 0; i < 4; ++i) {
        const int rbase = w * 32 + i * 8;
        int arow = m0 + rbase + lrow; if (arow > Mc) arow = Mc;
        gA[i] = A + (size_t)arow * 768 + lslot * 8;
        gB[i] = Bw + (size_t)(n0 + rbase + lrow) * 768 + lslot * 8;
    }

    f32x4 acc[4][4];
    #pragma unroll
    for (int i = 0; i < 4; ++i)
        #pragma unroll
        for (int j = 0; j < 4; ++j) acc[i][j] = (f32x4){0.f, 0.f, 0.f, 0.f};

#define STAGE(KT, DB) do {                                                      \
    _Pragma("unroll") for (int _i = 0; _i < 4; ++_i) {                          \
        const int _rb = w * 32 + _i * 8;                                        \
        __builtin_amdgcn_global_load_lds((gptr_t)(const void*)(gA[_i] + (KT) * 64), \
            (lptr_t)(void*)(&As[DB][_rb * 64]), 16, 0, 0);                      \
        __builtin_amdgcn_global_load_lds((gptr_t)(const void*)(gB[_i] + (KT) * 64), \
            (lptr_t)(void*)(&Bs[DB][_rb * 64]), 16, 0, 0);                      \
    }                                                                           \
} while (0)

#define GITER(KS, VM, DOSTG) do {                                               \
    asm volatile("s_waitcnt vmcnt(" #VM ")" ::: "memory");                      \
    __builtin_amdgcn_s_barrier();                                               \
    const int _db = (KS) & 1;                                                   \
    bf16x8 _af[8], _bf[8];                                                      \
    _Pragma("unroll") for (int _kk = 0; _kk < 2; ++_kk)                         \
        _Pragma("unroll") for (int _mf = 0; _mf < 4; ++_mf) {                   \
            _af[_kk * 4 + _mf] = *(const bf16x8*)(                              \
                &As[_db][(wr * 64 + _mf * 16 + l15) * 64 + (_kk * 4 + lg) * 8]);\
            _bf[_kk * 4 + _mf] = *(const bf16x8*)(                              \
                &Bs[_db][(wc * 64 + _mf * 16 + l15) * 64 + (_kk * 4 + lg) * 8]);\
        }                                                                       \
    asm volatile("s_waitcnt lgkmcnt(0)" ::: "memory");                          \
    __builtin_amdgcn_s_barrier();                                               \
    if (DOSTG) { STAGE((KS) + 2, _db); }                                        \
    __builtin_amdgcn_sched_barrier(0);                                          \
    __builtin_amdgcn_s_setprio(1);                                              \
    _Pragma("unroll") for (int _kk = 0; _kk < 2; ++_kk)                         \
        _Pragma("unroll") for (int _mf = 0; _mf < 4; ++_mf)                     \
            _Pragma("unroll") for (int _nf = 0; _nf < 4; ++_nf)                 \
                acc[_mf][_nf] = __builtin_amdgcn_mfma_f32_16x16x32_bf16(        \
                    _af[_kk * 4 + _mf], _bf[_kk * 4 + _nf], acc[_mf][_nf], 0, 0, 0); \
    __builtin_amdgcn_s_setprio(0);                                              \
} while (0)

    // prologue: stage tiles 0,1 (16 outstanding per wave)
    STAGE(0, 0);
    STAGE(1, 1);

    GITER(0, 8, 1);
    GITER(1, 8, 1);
    GITER(2, 8, 1);
    GITER(3, 8, 1);
    GITER(4, 8, 1);
    GITER(5, 8, 1);
    GITER(6, 8, 1);
    GITER(7, 8, 1);
    GITER(8, 8, 1);
    GITER(9, 8, 1);
    GITER(10, 8, 0);
    GITER(11, 0, 0);

#undef GITER
#undef STAGE

    #pragma unroll
    for (int mf = 0; mf < 4; ++mf) {
        #pragma unroll
        for (int nf = 0; nf < 4; ++nf) {
            int col = n0 + wc * 64 + nf * 16 + l15;
            float bb = 0.f;
            if (F32OUT) bb = bias[col];
            #pragma unroll
            for (int rr = 0; rr < 4; ++rr) {
                int m = m0 + wr * 64 + mf * 16 + lg * 4 + rr;
                if (m < M) {
                    if (F32OUT) Cf[(size_t)m * ldc + col] = acc[mf][nf][rr] + bb;
                    else        Cb[(size_t)m * ldc + col] = f2bf(acc[mf][nf][rr]);
                }
            }
        }
    }
}

// ---------------------------------------------------------------------------
// vtrans: Vt[b][h][d][j(448)] = KV[b*393+j][768 + h*64 + d]  (j>=393 -> 0)
// ---------------------------------------------------------------------------
__global__ __launch_bounds__(256) void vtrans_kernel(const u16* __restrict__ KV,
                                                     u16* __restrict__ Vt)
{
    const int bh = blockIdx.x;
    const int b = bh / H_, h = bh % H_;
    const int t = threadIdx.x, w = t >> 6, l = t & 63;
    const int d = w * 16 + (l >> 2);
    const int c = l & 3;
    const u16* src = KV + (size_t)b * N_ * 1536 + 768 + h * HD_ + d;
    u16* dst = Vt + (size_t)(bh * HD_ + d) * VTP;
    for (int jb = 0; jb < VTP; jb += 32) {
        int j0 = jb + c * 8;
        u16 v[8];
        #pragma unroll
        for (int i = 0; i < 8; ++i) {
            int j = j0 + i;
            v[i] = (j < N_) ? src[(size_t)j * 1536] : (u16)0;
        }
        *(bf16x8*)(dst + j0) = *(bf16x8*)v;
    }
}

// ---------------------------------------------------------------------------
// attention v5 (unchanged from round 11)
// ---------------------------------------------------------------------------
__global__ __launch_bounds__(256, 2) void attn_mfma5(
    const u16* __restrict__ qh, const u16* __restrict__ KV,
    const u16* __restrict__ Vt, const float* __restrict__ biasT,
    u16* __restrict__ Obuf)
{
    __shared__ __align__(16) u16 pts[64 * 456];
    __shared__ __align__(16) u16 kvs[2][64 * 64];

    const int id = blockIdx.x;
    const int work = (id & 7) * 384 + (id >> 3);
    const int ptile = work & 3;
    const int rest = work >> 2;
    const int h = rest % 12;
    const int b = rest / 12;
    const int p0 = ptile * 64;

    const int t = threadIdx.x, w = t >> 6, l = t & 63;
    const int l15 = l & 15, lg = l >> 4;
    const int p0w = p0 + w * 16;

    int srow[2], sslot[2], swoff[2];
    #pragma unroll
    for (int i = 0; i < 2; ++i) {
        int c = t + 256 * i;
        srow[i] = c >> 3; sslot[i] = c & 7;
        swoff[i] = srow[i] * 64 + ((sslot[i] ^ (srow[i] & 7)) << 3);
    }

    int prow = p0w + l15; if (prow > P_ - 1) prow = P_ - 1;
    const u16* qp = qh + (size_t)prow * C_ + h * HD_ + lg * 8;
    bf16x8 qf0 = *(const bf16x8*)(qp);
    bf16x8 qf1 = *(const bf16x8*)(qp + 32);

    const u16* Kbase = KV + (size_t)b * (N_ * 1536) + h * HD_;
    const u16* Vbase = Vt + (size_t)(b * H_ + h) * (HD_ * VTP);

    f32x4 acc[7][4];
    #pragma unroll
    for (int i = 0; i < 7; ++i)
        #pragma unroll
        for (int j = 0; j < 4; ++j) acc[i][j] = (f32x4){0.f, 0.f, 0.f, 0.f};

    // ---------------- pass 1: QK^T ----------------
    bf16x8 ra[2];
    #pragma unroll
    for (int i = 0; i < 2; ++i)
        ra[i] = *(const bf16x8*)(Kbase + (size_t)srow[i] * 1536 + sslot[i] * 8);
    #pragma unroll
    for (int i = 0; i < 2; ++i) *(bf16x8*)(&kvs[0][swoff[i]]) = ra[i];
    __syncthreads();

    #pragma unroll
    for (int nt = 0; nt < 7; ++nt) {
        const u16* kcur = kvs[nt & 1];
        if (nt < 6) {
            #pragma unroll
            for (int i = 0; i < 2; ++i) {
                int rn = (nt + 1) * 64 + srow[i]; if (rn > N_ - 1) rn = N_ - 1;
                ra[i] = *(const bf16x8*)(Kbase + (size_t)rn * 1536 + sslot[i] * 8);
            }
        }
        const int smax = (nt == 6) ? 1 : 4;
        __builtin_amdgcn_s_setprio(1);
        #pragma unroll
        for (int kc = 0; kc < 2; ++kc)
            #pragma unroll
            for (int sub = 0; sub < smax; ++sub) {
                int row = sub * 16 + l15;
                bf16x8 kb = *(const bf16x8*)(kcur + row * 64 + (((kc * 4 + lg) ^ (row & 7)) << 3));
                acc[nt][sub] = __builtin_amdgcn_mfma_f32_16x16x32_bf16(
                    kc ? qf1 : qf0, kb, acc[nt][sub], 0, 0, 0);
            }
        __builtin_amdgcn_s_setprio(0);
        if (nt < 6) {
            #pragma unroll
            for (int i = 0; i < 2; ++i) *(bf16x8*)(&kvs[(nt + 1) & 1][swoff[i]]) = ra[i];
        }
        __syncthreads();
    }

    // issue V tile 0 loads; softmax hides latency (T14)
    #pragma unroll
    for (int i = 0; i < 2; ++i)
        ra[i] = *(const bf16x8*)(Vbase + (size_t)srow[i] * VTP + sslot[i] * 8);

    // ---------------- single-pass softmax ----------------
    const int pcl = (p0w + lg * 4) > (PPAD - 4) ? (PPAD - 4) : (p0w + lg * 4);
    float s4[4] = {0.f, 0.f, 0.f, 0.f};
    #pragma unroll
    for (int nt = 0; nt < 7; ++nt) {
        const int smax = (nt == 6) ? 1 : 4;
        #pragma unroll
        for (int sub = 0; sub < smax; ++sub) {
            int n = nt * 64 + sub * 16 + l15;
            if (n < N_) {
                float4 b4 = *(const float4*)(biasT + ((size_t)h * BIAS_N + n) * PPAD + pcl);
                float bb[4] = {b4.x, b4.y, b4.z, b4.w};
                #pragma unroll
                for (int rr = 0; rr < 4; ++rr) {
                    float e = exp2_fast(fmaf(acc[nt][sub][rr], SCALE_L2E, bb[rr]));
                    acc[nt][sub][rr] = e;
                    s4[rr] += e;
                }
            } else {
                acc[nt][sub] = (f32x4){0.f, 0.f, 0.f, 0.f};
            }
        }
    }
    float rinv4[4];
    #pragma unroll
    for (int rr = 0; rr < 4; ++rr) {
        float s = s4[rr];
        s += __shfl_xor(s, 1); s += __shfl_xor(s, 2);
        s += __shfl_xor(s, 4); s += __shfl_xor(s, 8);
        rinv4[rr] = 1.0f / s;
    }

    // ---------------- P (unnormalized) -> LDS bf16 ----------------
    {
        const int rowb = w * 16 + lg * 4;
        #pragma unroll
        for (int nt = 0; nt < 7; ++nt) {
            const int smax = (nt == 6) ? 1 : 4;
            #pragma unroll
            for (int sub = 0; sub < smax; ++sub) {
                int col = nt * 64 + sub * 16 + l15;
                unsigned pk01 = cvt_pk_bf16(acc[nt][sub][0], acc[nt][sub][1]);
                unsigned pk23 = cvt_pk_bf16(acc[nt][sub][2], acc[nt][sub][3]);
                pts[(rowb + 0) * 456 + col] = (u16)pk01;
                pts[(rowb + 1) * 456 + col] = (u16)(pk01 >> 16);
                pts[(rowb + 2) * 456 + col] = (u16)pk23;
                pts[(rowb + 3) * 456 + col] = (u16)(pk23 >> 16);
            }
        }
        #pragma unroll
        for (int rr = 0; rr < 4; ++rr)
            pts[(rowb + rr) * 456 + 400 + l15] = 0;
    }
    #pragma unroll
    for (int i = 0; i < 2; ++i) *(bf16x8*)(&kvs[0][swoff[i]]) = ra[i];
    __syncthreads();

    // ---------------- pass 2: PV ----------------
    f32x4 o[4];
    #pragma unroll
    for (int i = 0; i < 4; ++i) o[i] = (f32x4){0.f, 0.f, 0.f, 0.f};

    #pragma unroll
    for (int nt = 0; nt < 7; ++nt) {
        const u16* kcur = kvs[nt & 1];
        if (nt < 6) {
            #pragma unroll
            for (int i = 0; i < 2; ++i)
                ra[i] = *(const bf16x8*)(Vbase + (size_t)srow[i] * VTP + (nt + 1) * 64 + sslot[i] * 8);
        }
        const int kcmax = (nt == 6) ? 1 : 2;
        __builtin_amdgcn_s_setprio(1);
        #pragma unroll
        for (int kc = 0; kc < kcmax; ++kc) {
            bf16x8 pa = *(const bf16x8*)(pts + (w * 16 + l15) * 456 + nt * 64 + kc * 32 + lg * 8);
            #pragma unroll
            for (int dsub = 0; dsub < 4; ++dsub) {
                int row = dsub * 16 + l15;
                bf16x8 vb = *(const bf16x8*)(kcur + row * 64 + (((kc * 4 + lg) ^ (row & 7)) << 3));
                o[dsub] = __builtin_amdgcn_mfma_f32_16x16x32_bf16(pa, vb, o[dsub], 0, 0, 0);
            }
        }
        __builtin_amdgcn_s_setprio(0);
        if (nt < 6) {
            #pragma unroll
            for (int i = 0; i < 2; ++i) *(bf16x8*)(&kvs[(nt + 1) & 1][swoff[i]]) = ra[i];
        }
        __syncthreads();
    }

    // ---------------- store (normalize here) ----------------
    #pragma unroll
    for (int dsub = 0; dsub < 4; ++dsub)
        #pragma unroll
        for (int rr = 0; rr < 4; ++rr) {
            int p = p0w + lg * 4 + rr;
            if (p < P_)
                Obuf[((size_t)b * P_ + p) * C_ + h * HD_ + dsub * 16 + l15] =
                    f2bf(o[dsub][rr] * rinv4[rr]);
        }
}

// ---------------------------------------------------------------------------
extern "C" void kernel_launch(void* const* d_in, const int* in_sizes, int n_in,
                              void* d_out, int out_size, void* d_ws, size_t ws_size,
                              hipStream_t stream)
{
    const float* x         = (const float*)d_in[0];
    const float* q_learned = (const float*)d_in[1];
    const float* pos_embed = (const float*)d_in[2];
    const float* wk        = (const float*)d_in[3];
    const float* wv        = (const float*)d_in[4];
    const float* rpe_w     = (const float*)d_in[5];
    const float* proj_w    = (const float*)d_in[6];
    const float* proj_b    = (const float*)d_in[7];
    const int*   rp_bucket = (const int*)d_in[8];
    float* out = (float*)d_out;

    char* ws = (char*)d_ws;
    u16*   xh    = (u16*)(ws);                        // 38,633,472 B
    u16*   wkvh  = (u16*)(ws + 38633472);             //  2,359,296 B
    u16*   pwh   = (u16*)(ws + 40992768);             //  1,179,648 B
    u16*   qh    = (u16*)(ws + 42172416);             //    302,592 B
    float* lk    = (float*)(ws + 42475008);           //     75,776 B
    float* biasT = (float*)(ws + 42550784);           //  4,153,344 B
    u16*   KV    = (u16*)(ws + 46704128);             // 77,266,944 B
    u16*   Vt    = (u16*)(ws + 123971072);            // 44,040,192 B
    u16*   Obuf  = (u16*)(ws + 168011264);            // 19,365,888 B (end ~179 MB)

    conv_all<<<20592, 256, 0, stream>>>(x, wk, wv, proj_w, xh, wkvh, pwh);

    prep1_kernel<<<P_, 256, 0, stream>>>(q_learned, pos_embed, rpe_w, qh, lk);
    prep2_kernel<<<H_ * N_, 256, 0, stream>>>(lk, rp_bucket, biasT);

    dim3 gkv(1536 / 128, (M_KV + 127) / 128);   // 12 x 197
    gemm_bf16<false><<<gkv, 256, 0, stream>>>(xh, wkvh, KV, nullptr, nullptr, M_KV, 1536);

    vtrans_kernel<<<B_ * H_, 256, 0, stream>>>(KV, Vt);

    attn_mfma5<<<3072, 256, 0, stream>>>(qh, KV, Vt, biasT, Obuf);

    dim3 gpr(768 / 128, (M_PR + 127) / 128);    // 6 x 99
    gemm_bf16<true><<<gpr, 256, 0, stream>>>(Obuf, pwh, nullptr, out, proj_b, M_PR, 768);
}

// Round 13
// 227.976 us; speedup vs baseline: 1.0901x; 1.0901x over previous
//
#include <hip/hip_runtime.h>

typedef unsigned short u16;
typedef short bf16x8 __attribute__((ext_vector_type(8)));
typedef float f32x4 __attribute__((ext_vector_type(4)));
typedef const __attribute__((address_space(1))) void* gptr_t;
typedef __attribute__((address_space(3))) void* lptr_t;

#define B_   64
#define N_   393
#define C_   768
#define H_   12
#define HD_  64
#define P_   197
#define BIAS_N 416
#define PPAD 208
#define VTP  448
#define M_KV (B_ * N_)   // 25152
#define M_PR (B_ * P_)   // 12608
#define SCALE_L2E 0.180336879f   // 0.125 * log2(e)

__device__ __forceinline__ u16 f2bf(float f) {
    unsigned u = __float_as_uint(f);
    return (u16)((u + 0x7FFFu + ((u >> 16) & 1u)) >> 16);
}
__device__ __forceinline__ unsigned cvt_pk_bf16(float lo, float hi) {
    unsigned r;
    asm("v_cvt_pk_bf16_f32 %0, %1, %2" : "=v"(r) : "v"(lo), "v"(hi));
    return r;
}
__device__ __forceinline__ float exp2_fast(float x) {
    float r;
    asm("v_exp_f32 %0, %1" : "=v"(r) : "v"(x));
    return r;
}

// ---------------------------------------------------------------------------
// conv_prep1: fused {fp32->bf16 for x,wk,wv,proj_w} + {prep1} in one launch.
// blocks [0, 20592): conversion; blocks [20592, 20789): prep1 (p = bx-20592).
// ---------------------------------------------------------------------------
__global__ __launch_bounds__(256) void conv_prep1(
    const float* __restrict__ x, const float* __restrict__ wk,
    const float* __restrict__ wv, const float* __restrict__ pw,
    const float* __restrict__ q_learned, const float* __restrict__ pos_embed,
    const float* __restrict__ rpe_w,
    u16* __restrict__ xh, u16* __restrict__ wkvh, u16* __restrict__ pwh,
    u16* __restrict__ qh, float* __restrict__ lk)
{
    __shared__ float q_s[C_];
    const int bx = blockIdx.x, t = threadIdx.x;
    if (bx < 20592) {
        const int XN4 = 19316736 / 4;
        const int WN4 = 589824 / 4;
        int i = bx * 256 + t;
        const float* src; u16* dst; int off;
        if (i < XN4) { src = x; dst = xh; off = i; }
        else {
            int j = i - XN4;
            int sec = j / WN4;
            off = j - sec * WN4;
            src = sec == 0 ? wk : (sec == 1 ? wv : pw);
            dst = sec == 0 ? wkvh : (sec == 1 ? wkvh + 589824 : pwh);
        }
        float4 v = ((const float4*)src)[off];
        u16 o[4] = {f2bf(v.x), f2bf(v.y), f2bf(v.z), f2bf(v.w)};
        *(uint2*)(dst + off * 4) = *(uint2*)o;
    } else {
        const int p = bx - 20592;
        for (int c = t; c < C_; c += 256) {
            float v = q_learned[c] + pos_embed[p * C_ + c];
            q_s[c] = v;
            qh[p * C_ + c] = f2bf(v);
        }
        __syncthreads();
        if (t < H_ * 8) {
            int h = t >> 3, u = t & 7;
            float s = 0.f;
            #pragma unroll 8
            for (int d = 0; d < HD_; ++d)
                s = fmaf(q_s[h * HD_ + d], rpe_w[d * 8 + u], s);
            lk[(h * P_ + p) * 8 + u] = s;
        }
    }
}

// ---------------------------------------------------------------------------
// Templated 128x128x64 bf16 MFMA GEMM, m97 structure (known-good, 91 us):
// global_load_lds(16B) into linear LDS [128][64], 2-barrier K-loop,
// bijective XCD swizzle, dense coalesced epilogue.  (r11 revert)
// ---------------------------------------------------------------------------
template <bool F32OUT>
__global__ __launch_bounds__(256) void gemm_bf16(
    const u16* __restrict__ A, const u16* __restrict__ Bw,
    u16* __restrict__ Cb, float* __restrict__ Cf, const float* __restrict__ bias,
    int M, int ldc)
{
    __shared__ __align__(16) u16 As[128 * 64];
    __shared__ __align__(16) u16 Bs[128 * 64];

    const int gx = gridDim.x;
    const int nwg = gx * gridDim.y;
    const int orig = blockIdx.y * gx + blockIdx.x;
    const int xcd = orig & 7, rank = orig >> 3;
    const int q = nwg >> 3, r = nwg & 7;
    const int wgid = (xcd < r ? xcd * (q + 1) : r * (q + 1) + (xcd - r) * q) + rank;
    const int n0 = (wgid % gx) * 128;
    const int m0 = (wgid / gx) * 128;

    const int t = threadIdx.x;
    const int w = t >> 6, l = t & 63;
    const int wr = w >> 1, wc = w & 1;
    const int l15 = l & 15, lg = l >> 4;
    const int lrow = l >> 3, lslot = l & 7;
    const int Mc = M - 1;

    f32x4 acc[4][4];
    #pragma unroll
    for (int i = 0; i < 4; ++i)
        #pragma unroll
        for (int j = 0; j < 4; ++j) acc[i][j] = (f32x4){0.f, 0.f, 0.f, 0.f};

    for (int ks = 0; ks < 12; ++ks) {
        const int k0 = ks * 64;
        if (ks) __syncthreads();          // previous tile fully consumed
        #pragma unroll
        for (int i = 0; i < 4; ++i) {
            const int rbase = w * 32 + i * 8;        // 8 rows per issue
            int arow = m0 + rbase + lrow; if (arow > Mc) arow = Mc;
            const int brow = n0 + rbase + lrow;
            const u16* ga = A  + (size_t)arow * 768 + k0 + lslot * 8;
            const u16* gb = Bw + (size_t)brow * 768 + k0 + lslot * 8;
            __builtin_amdgcn_global_load_lds((gptr_t)(const void*)ga,
                                             (lptr_t)(void*)(As + rbase * 64), 16, 0, 0);
            __builtin_amdgcn_global_load_lds((gptr_t)(const void*)gb,
                                             (lptr_t)(void*)(Bs + rbase * 64), 16, 0, 0);
        }
        __syncthreads();                  // drains vmcnt: tile resident
        #pragma unroll
        for (int kk = 0; kk < 2; ++kk) {
            bf16x8 af[4], bfr[4];
            #pragma unroll
            for (int mf = 0; mf < 4; ++mf) {
                af[mf]  = *(const bf16x8*)(As + (wr * 64 + mf * 16 + l15) * 64 + (kk * 4 + lg) * 8);
                bfr[mf] = *(const bf16x8*)(Bs + (wc * 64 + mf * 16 + l15) * 64 + (kk * 4 + lg) * 8);
            }
            #pragma unroll
            for (int mf = 0; mf < 4; ++mf)
                #pragma unroll
                for (int nf = 0; nf < 4; ++nf)
                    acc[mf][nf] = __builtin_amdgcn_mfma_f32_16x16x32_bf16(
                        af[mf], bfr[nf], acc[mf][nf], 0, 0, 0);
        }
    }

    #pragma unroll
    for (int mf = 0; mf < 4; ++mf) {
        #pragma unroll
        for (int nf = 0; nf < 4; ++nf) {
            int col = n0 + wc * 64 + nf * 16 + l15;
            float bb = 0.f;
            if (F32OUT) bb = bias[col];
            #pragma unroll
            for (int rr = 0; rr < 4; ++rr) {
                int m = m0 + wr * 64 + mf * 16 + lg * 4 + rr;
                if (m < M) {
                    if (F32OUT) Cf[(size_t)m * ldc + col] = acc[mf][nf][rr] + bb;
                    else        Cb[(size_t)m * ldc + col] = f2bf(acc[mf][nf][rr]);
                }
            }
        }
    }
}

// ---------------------------------------------------------------------------
// vtrans_prep2: fused {coalesced V transpose} + {prep2} in one launch.
// blocks [0, 768): vtrans via 64x64 LDS tile (16B coalesced reads+writes);
// blocks [768, 5484): prep2 (i = bx-768).
// ---------------------------------------------------------------------------
__global__ __launch_bounds__(256) void vtrans_prep2(
    const u16* __restrict__ KV, u16* __restrict__ Vt,
    const float* __restrict__ lk, const int* __restrict__ rp_bucket,
    float* __restrict__ biasT)
{
    __shared__ __align__(16) u16 vts[64][68];   // +4 pad
    const int bx = blockIdx.x, t = threadIdx.x;
    if (bx < B_ * H_) {
        const int b = bx / H_, h = bx % H_;
        const u16* src = KV + (size_t)b * N_ * 1536 + 768 + h * HD_;
        u16* dst = Vt + (size_t)bx * HD_ * VTP;
        for (int jt = 0; jt < 7; ++jt) {
            const int j0 = jt * 64;
            if (jt) __syncthreads();      // prior tile's LDS reads done
            #pragma unroll
            for (int ps = 0; ps < 2; ++ps) {
                int jr = ps * 32 + (t >> 3);
                int dd = (t & 7) * 8;
                int j = j0 + jr;
                bf16x8 v = (bf16x8){0, 0, 0, 0, 0, 0, 0, 0};
                if (j < N_) v = *(const bf16x8*)(src + (size_t)j * 1536 + dd);
                *(bf16x8*)(&vts[jr][dd]) = v;
            }
            __syncthreads();
            #pragma unroll
            for (int ps = 0; ps < 2; ++ps) {
                int idx = t + 256 * ps;
                int d = idx >> 3, ch = idx & 7;
                u16 v[8];
                #pragma unroll
                for (int k = 0; k < 8; ++k) v[k] = vts[ch * 8 + k][d];
                *(bf16x8*)(dst + (size_t)d * VTP + j0 + ch * 8) = *(bf16x8*)v;
            }
        }
    } else {
        const int i = bx - B_ * H_;
        const int h = i / N_, j = i % N_;
        if (t >= PPAD) return;
        int jm;
        if (j == 0) jm = 0;
        else { jm = j - 1; if (jm >= 196) jm -= 196; jm += 1; }
        float v = 0.f;
        if (t < P_) {
            int bucket = rp_bucket[t * P_ + jm];
            v = lk[(h * P_ + t) * 8 + bucket] * 1.44269504f;
        }
        biasT[((size_t)h * BIAS_N + j) * PPAD + t] = v;
    }
}

// ---------------------------------------------------------------------------
// attention v5 (unchanged from round 11)
// ---------------------------------------------------------------------------
__global__ __launch_bounds__(256, 2) void attn_mfma5(
    const u16* __restrict__ qh, const u16* __restrict__ KV,
    const u16* __restrict__ Vt, const float* __restrict__ biasT,
    u16* __restrict__ Obuf)
{
    __shared__ __align__(16) u16 pts[64 * 456];
    __shared__ __align__(16) u16 kvs[2][64 * 64];

    const int id = blockIdx.x;
    const int work = (id & 7) * 384 + (id >> 3);
    const int ptile = work & 3;
    const int rest = work >> 2;
    const int h = rest % 12;
    const int b = rest / 12;
    const int p0 = ptile * 64;

    const int t = threadIdx.x, w = t >> 6, l = t & 63;
    const int l15 = l & 15, lg = l >> 4;
    const int p0w = p0 + w * 16;

    int srow[2], sslot[2], swoff[2];
    #pragma unroll
    for (int i = 0; i < 2; ++i) {
        int c = t + 256 * i;
        srow[i] = c >> 3; sslot[i] = c & 7;
        swoff[i] = srow[i] * 64 + ((sslot[i] ^ (srow[i] & 7)) << 3);
    }

    int prow = p0w + l15; if (prow > P_ - 1) prow = P_ - 1;
    const u16* qp = qh + (size_t)prow * C_ + h * HD_ + lg * 8;
    bf16x8 qf0 = *(const bf16x8*)(qp);
    bf16x8 qf1 = *(const bf16x8*)(qp + 32);

    const u16* Kbase = KV + (size_t)b * (N_ * 1536) + h * HD_;
    const u16* Vbase = Vt + (size_t)(b * H_ + h) * (HD_ * VTP);

    f32x4 acc[7][4];
    #pragma unroll
    for (int i = 0; i < 7; ++i)
        #pragma unroll
        for (int j = 0; j < 4; ++j) acc[i][j] = (f32x4){0.f, 0.f, 0.f, 0.f};

    // ---------------- pass 1: QK^T ----------------
    bf16x8 ra[2];
    #pragma unroll
    for (int i = 0; i < 2; ++i)
        ra[i] = *(const bf16x8*)(Kbase + (size_t)srow[i] * 1536 + sslot[i] * 8);
    #pragma unroll
    for (int i = 0; i < 2; ++i) *(bf16x8*)(&kvs[0][swoff[i]]) = ra[i];
    __syncthreads();

    #pragma unroll
    for (int nt = 0; nt < 7; ++nt) {
        const u16* kcur = kvs[nt & 1];
        if (nt < 6) {
            #pragma unroll
            for (int i = 0; i < 2; ++i) {
                int rn = (nt + 1) * 64 + srow[i]; if (rn > N_ - 1) rn = N_ - 1;
                ra[i] = *(const bf16x8*)(Kbase + (size_t)rn * 1536 + sslot[i] * 8);
            }
        }
        const int smax = (nt == 6) ? 1 : 4;
        __builtin_amdgcn_s_setprio(1);
        #pragma unroll
        for (int kc = 0; kc < 2; ++kc)
            #pragma unroll
            for (int sub = 0; sub < smax; ++sub) {
                int row = sub * 16 + l15;
                bf16x8 kb = *(const bf16x8*)(kcur + row * 64 + (((kc * 4 + lg) ^ (row & 7)) << 3));
                acc[nt][sub] = __builtin_amdgcn_mfma_f32_16x16x32_bf16(
                    kc ? qf1 : qf0, kb, acc[nt][sub], 0, 0, 0);
            }
        __builtin_amdgcn_s_setprio(0);
        if (nt < 6) {
            #pragma unroll
            for (int i = 0; i < 2; ++i) *(bf16x8*)(&kvs[(nt + 1) & 1][swoff[i]]) = ra[i];
        }
        __syncthreads();
    }

    // issue V tile 0 loads; softmax hides latency (T14)
    #pragma unroll
    for (int i = 0; i < 2; ++i)
        ra[i] = *(const bf16x8*)(Vbase + (size_t)srow[i] * VTP + sslot[i] * 8);

    // ---------------- single-pass softmax ----------------
    const int pcl = (p0w + lg * 4) > (PPAD - 4) ? (PPAD - 4) : (p0w + lg * 4);
    float s4[4] = {0.f, 0.f, 0.f, 0.f};
    #pragma unroll
    for (int nt = 0; nt < 7; ++nt) {
        const int smax = (nt == 6) ? 1 : 4;
        #pragma unroll
        for (int sub = 0; sub < smax; ++sub) {
            int n = nt * 64 + sub * 16 + l15;
            if (n < N_) {
                float4 b4 = *(const float4*)(biasT + ((size_t)h * BIAS_N + n) * PPAD + pcl);
                float bb[4] = {b4.x, b4.y, b4.z, b4.w};
                #pragma unroll
                for (int rr = 0; rr < 4; ++rr) {
                    float e = exp2_fast(fmaf(acc[nt][sub][rr], SCALE_L2E, bb[rr]));
                    acc[nt][sub][rr] = e;
                    s4[rr] += e;
                }
            } else {
                acc[nt][sub] = (f32x4){0.f, 0.f, 0.f, 0.f};
            }
        }
    }
    float rinv4[4];
    #pragma unroll
    for (int rr = 0; rr < 4; ++rr) {
        float s = s4[rr];
        s += __shfl_xor(s, 1); s += __shfl_xor(s, 2);
        s += __shfl_xor(s, 4); s += __shfl_xor(s, 8);
        rinv4[rr] = 1.0f / s;
    }

    // ---------------- P (unnormalized) -> LDS bf16 ----------------
    {
        const int rowb = w * 16 + lg * 4;
        #pragma unroll
        for (int nt = 0; nt < 7; ++nt) {
            const int smax = (nt == 6) ? 1 : 4;
            #pragma unroll
            for (int sub = 0; sub < smax; ++sub) {
                int col = nt * 64 + sub * 16 + l15;
                unsigned pk01 = cvt_pk_bf16(acc[nt][sub][0], acc[nt][sub][1]);
                unsigned pk23 = cvt_pk_bf16(acc[nt][sub][2], acc[nt][sub][3]);
                pts[(rowb + 0) * 456 + col] = (u16)pk01;
                pts[(rowb + 1) * 456 + col] = (u16)(pk01 >> 16);
                pts[(rowb + 2) * 456 + col] = (u16)pk23;
                pts[(rowb + 3) * 456 + col] = (u16)(pk23 >> 16);
            }
        }
        #pragma unroll
        for (int rr = 0; rr < 4; ++rr)
            pts[(rowb + rr) * 456 + 400 + l15] = 0;
    }
    #pragma unroll
    for (int i = 0; i < 2; ++i) *(bf16x8*)(&kvs[0][swoff[i]]) = ra[i];
    __syncthreads();

    // ---------------- pass 2: PV ----------------
    f32x4 o[4];
    #pragma unroll
    for (int i = 0; i < 4; ++i) o[i] = (f32x4){0.f, 0.f, 0.f, 0.f};

    #pragma unroll
    for (int nt = 0; nt < 7; ++nt) {
        const u16* kcur = kvs[nt & 1];
        if (nt < 6) {
            #pragma unroll
            for (int i = 0; i < 2; ++i)
                ra[i] = *(const bf16x8*)(Vbase + (size_t)srow[i] * VTP + (nt + 1) * 64 + sslot[i] * 8);
        }
        const int kcmax = (nt == 6) ? 1 : 2;
        __builtin_amdgcn_s_setprio(1);
        #pragma unroll
        for (int kc = 0; kc < kcmax; ++kc) {
            bf16x8 pa = *(const bf16x8*)(pts + (w * 16 + l15) * 456 + nt * 64 + kc * 32 + lg * 8);
            #pragma unroll
            for (int dsub = 0; dsub < 4; ++dsub) {
                int row = dsub * 16 + l15;
                bf16x8 vb = *(const bf16x8*)(kcur + row * 64 + (((kc * 4 + lg) ^ (row & 7)) << 3));
                o[dsub] = __builtin_amdgcn_mfma_f32_16x16x32_bf16(pa, vb, o[dsub], 0, 0, 0);
            }
        }
        __builtin_amdgcn_s_setprio(0);
        if (nt < 6) {
            #pragma unroll
            for (int i = 0; i < 2; ++i) *(bf16x8*)(&kvs[(nt + 1) & 1][swoff[i]]) = ra[i];
        }
        __syncthreads();
    }

    // ---------------- store (normalize here) ----------------
    #pragma unroll
    for (int dsub = 0; dsub < 4; ++dsub)
        #pragma unroll
        for (int rr = 0; rr < 4; ++rr) {
            int p = p0w + lg * 4 + rr;
            if (p < P_)
                Obuf[((size_t)b * P_ + p) * C_ + h * HD_ + dsub * 16 + l15] =
                    f2bf(o[dsub][rr] * rinv4[rr]);
        }
}

// ---------------------------------------------------------------------------
extern "C" void kernel_launch(void* const* d_in, const int* in_sizes, int n_in,
                              void* d_out, int out_size, void* d_ws, size_t ws_size,
                              hipStream_t stream)
{
    const float* x         = (const float*)d_in[0];
    const float* q_learned = (const float*)d_in[1];
    const float* pos_embed = (const float*)d_in[2];
    const float* wk        = (const float*)d_in[3];
    const float* wv        = (const float*)d_in[4];
    const float* rpe_w     = (const float*)d_in[5];
    const float* proj_w    = (const float*)d_in[6];
    const float* proj_b    = (const float*)d_in[7];
    const int*   rp_bucket = (const int*)d_in[8];
    float* out = (float*)d_out;

    char* ws = (char*)d_ws;
    u16*   xh    = (u16*)(ws);                        // 38,633,472 B
    u16*   wkvh  = (u16*)(ws + 38633472);             //  2,359,296 B
    u16*   pwh   = (u16*)(ws + 40992768);             //  1,179,648 B
    u16*   qh    = (u16*)(ws + 42172416);             //    302,592 B
    float* lk    = (float*)(ws + 42475008);           //     75,776 B
    float* biasT = (float*)(ws + 42550784);           //  4,153,344 B
    u16*   KV    = (u16*)(ws + 46704128);             // 77,266,944 B
    u16*   Vt    = (u16*)(ws + 123971072);            // 44,040,192 B
    u16*   Obuf  = (u16*)(ws + 168011264);            // 19,365,888 B (end ~179 MB)

    // launch 1: conversions + prep1  (20592 + 197 blocks)
    conv_prep1<<<20789, 256, 0, stream>>>(x, wk, wv, proj_w,
                                          q_learned, pos_embed, rpe_w,
                                          xh, wkvh, pwh, qh, lk);

    // launch 2: KV GEMM
    dim3 gkv(1536 / 128, (M_KV + 127) / 128);   // 12 x 197
    gemm_bf16<false><<<gkv, 256, 0, stream>>>(xh, wkvh, KV, nullptr, nullptr, M_KV, 1536);

    // launch 3: V transpose + prep2  (768 + 4716 blocks)
    vtrans_prep2<<<5484, 256, 0, stream>>>(KV, Vt, lk, rp_bucket, biasT);

    // launch 4: attention
    attn_mfma5<<<3072, 256, 0, stream>>>(qh, KV, Vt, biasT, Obuf);

    // launch 5: output projection
    dim3 gpr(768 / 128, (M_PR + 127) / 128);    // 6 x 99
    gemm_bf16<true><<<gpr, 256, 0, stream>>>(Obuf, pwh, nullptr, out, proj_b, M_PR, 768);
}

// Round 14
// 214.690 us; speedup vs baseline: 1.1576x; 1.0619x over previous
//
#include <hip/hip_runtime.h>

typedef unsigned short u16;
typedef short bf16x8 __attribute__((ext_vector_type(8)));
typedef float f32x4 __attribute__((ext_vector_type(4)));
typedef const __attribute__((address_space(1))) void* gptr_t;
typedef __attribute__((address_space(3))) void* lptr_t;

#define B_   64
#define N_   393
#define C_   768
#define H_   12
#define HD_  64
#define P_   197
#define BIAS_N 416
#define PPAD 208
#define VTP  448
#define M_KV (B_ * N_)   // 25152
#define M_PR (B_ * P_)   // 12608
#define SCALE_L2E 0.180336879f   // 0.125 * log2(e)
#define PPITCH 70

__device__ __forceinline__ u16 f2bf(float f) {
    unsigned u = __float_as_uint(f);
    return (u16)((u + 0x7FFFu + ((u >> 16) & 1u)) >> 16);
}
__device__ __forceinline__ unsigned cvt_pk_bf16(float lo, float hi) {
    unsigned r;
    asm("v_cvt_pk_bf16_f32 %0, %1, %2" : "=v"(r) : "v"(lo), "v"(hi));
    return r;
}
__device__ __forceinline__ float exp2_fast(float x) {
    float r;
    asm("v_exp_f32 %0, %1" : "=v"(r) : "v"(x));
    return r;
}

// ---------------------------------------------------------------------------
// conv_prep1: fused {fp32->bf16 for x,wk,wv,proj_w} + {prep1} (unchanged r13)
// ---------------------------------------------------------------------------
__global__ __launch_bounds__(256) void conv_prep1(
    const float* __restrict__ x, const float* __restrict__ wk,
    const float* __restrict__ wv, const float* __restrict__ pw,
    const float* __restrict__ q_learned, const float* __restrict__ pos_embed,
    const float* __restrict__ rpe_w,
    u16* __restrict__ xh, u16* __restrict__ wkvh, u16* __restrict__ pwh,
    u16* __restrict__ qh, float* __restrict__ lk)
{
    __shared__ float q_s[C_];
    const int bx = blockIdx.x, t = threadIdx.x;
    if (bx < 20592) {
        const int XN4 = 19316736 / 4;
        const int WN4 = 589824 / 4;
        int i = bx * 256 + t;
        const float* src; u16* dst; int off;
        if (i < XN4) { src = x; dst = xh; off = i; }
        else {
            int j = i - XN4;
            int sec = j / WN4;
            off = j - sec * WN4;
            src = sec == 0 ? wk : (sec == 1 ? wv : pw);
            dst = sec == 0 ? wkvh : (sec == 1 ? wkvh + 589824 : pwh);
        }
        float4 v = ((const float4*)src)[off];
        u16 o[4] = {f2bf(v.x), f2bf(v.y), f2bf(v.z), f2bf(v.w)};
        *(uint2*)(dst + off * 4) = *(uint2*)o;
    } else {
        const int p = bx - 20592;
        for (int c = t; c < C_; c += 256) {
            float v = q_learned[c] + pos_embed[p * C_ + c];
            q_s[c] = v;
            qh[p * C_ + c] = f2bf(v);
        }
        __syncthreads();
        if (t < H_ * 8) {
            int h = t >> 3, u = t & 7;
            float s = 0.f;
            #pragma unroll 8
            for (int d = 0; d < HD_; ++d)
                s = fmaf(q_s[h * HD_ + d], rpe_w[d * 8 + u], s);
            lk[(h * P_ + p) * 8 + u] = s;
        }
    }
}

// ---------------------------------------------------------------------------
// Templated 128x128x64 bf16 MFMA GEMM, m97 structure (known-good, 91 us)
// ---------------------------------------------------------------------------
template <bool F32OUT>
__global__ __launch_bounds__(256) void gemm_bf16(
    const u16* __restrict__ A, const u16* __restrict__ Bw,
    u16* __restrict__ Cb, float* __restrict__ Cf, const float* __restrict__ bias,
    int M, int ldc)
{
    __shared__ __align__(16) u16 As[128 * 64];
    __shared__ __align__(16) u16 Bs[128 * 64];

    const int gx = gridDim.x;
    const int nwg = gx * gridDim.y;
    const int orig = blockIdx.y * gx + blockIdx.x;
    const int xcd = orig & 7, rank = orig >> 3;
    const int q = nwg >> 3, r = nwg & 7;
    const int wgid = (xcd < r ? xcd * (q + 1) : r * (q + 1) + (xcd - r) * q) + rank;
    const int n0 = (wgid % gx) * 128;
    const int m0 = (wgid / gx) * 128;

    const int t = threadIdx.x;
    const int w = t >> 6, l = t & 63;
    const int wr = w >> 1, wc = w & 1;
    const int l15 = l & 15, lg = l >> 4;
    const int lrow = l >> 3, lslot = l & 7;
    const int Mc = M - 1;

    f32x4 acc[4][4];
    #pragma unroll
    for (int i = 0; i < 4; ++i)
        #pragma unroll
        for (int j = 0; j < 4; ++j) acc[i][j] = (f32x4){0.f, 0.f, 0.f, 0.f};

    for (int ks = 0; ks < 12; ++ks) {
        const int k0 = ks * 64;
        if (ks) __syncthreads();
        #pragma unroll
        for (int i = 0; i < 4; ++i) {
            const int rbase = w * 32 + i * 8;
            int arow = m0 + rbase + lrow; if (arow > Mc) arow = Mc;
            const int brow = n0 + rbase + lrow;
            const u16* ga = A  + (size_t)arow * 768 + k0 + lslot * 8;
            const u16* gb = Bw + (size_t)brow * 768 + k0 + lslot * 8;
            __builtin_amdgcn_global_load_lds((gptr_t)(const void*)ga,
                                             (lptr_t)(void*)(As + rbase * 64), 16, 0, 0);
            __builtin_amdgcn_global_load_lds((gptr_t)(const void*)gb,
                                             (lptr_t)(void*)(Bs + rbase * 64), 16, 0, 0);
        }
        __syncthreads();
        #pragma unroll
        for (int kk = 0; kk < 2; ++kk) {
            bf16x8 af[4], bfr[4];
            #pragma unroll
            for (int mf = 0; mf < 4; ++mf) {
                af[mf]  = *(const bf16x8*)(As + (wr * 64 + mf * 16 + l15) * 64 + (kk * 4 + lg) * 8);
                bfr[mf] = *(const bf16x8*)(Bs + (wc * 64 + mf * 16 + l15) * 64 + (kk * 4 + lg) * 8);
            }
            #pragma unroll
            for (int mf = 0; mf < 4; ++mf)
                #pragma unroll
                for (int nf = 0; nf < 4; ++nf)
                    acc[mf][nf] = __builtin_amdgcn_mfma_f32_16x16x32_bf16(
                        af[mf], bfr[nf], acc[mf][nf], 0, 0, 0);
        }
    }

    #pragma unroll
    for (int mf = 0; mf < 4; ++mf) {
        #pragma unroll
        for (int nf = 0; nf < 4; ++nf) {
            int col = n0 + wc * 64 + nf * 16 + l15;
            float bb = 0.f;
            if (F32OUT) bb = bias[col];
            #pragma unroll
            for (int rr = 0; rr < 4; ++rr) {
                int m = m0 + wr * 64 + mf * 16 + lg * 4 + rr;
                if (m < M) {
                    if (F32OUT) Cf[(size_t)m * ldc + col] = acc[mf][nf][rr] + bb;
                    else        Cb[(size_t)m * ldc + col] = f2bf(acc[mf][nf][rr]);
                }
            }
        }
    }
}

// ---------------------------------------------------------------------------
// vtrans_prep2: fused {coalesced V transpose} + {prep2 -> biasT2[h][p][416]}
// blocks [0,768): vtrans; blocks [768, 768+2496): prep2 (h=i/208, p=i%208)
// ---------------------------------------------------------------------------
__global__ __launch_bounds__(256) void vtrans_prep2(
    const u16* __restrict__ KV, u16* __restrict__ Vt,
    const float* __restrict__ lk, const int* __restrict__ rp_bucket,
    float* __restrict__ biasT2)
{
    __shared__ __align__(16) u16 vts[64][68];
    const int bx = blockIdx.x, t = threadIdx.x;
    if (bx < B_ * H_) {
        const int b = bx / H_, h = bx % H_;
        const u16* src = KV + (size_t)b * N_ * 1536 + 768 + h * HD_;
        u16* dst = Vt + (size_t)bx * HD_ * VTP;
        for (int jt = 0; jt < 7; ++jt) {
            const int j0 = jt * 64;
            if (jt) __syncthreads();
            #pragma unroll
            for (int ps = 0; ps < 2; ++ps) {
                int jr = ps * 32 + (t >> 3);
                int dd = (t & 7) * 8;
                int j = j0 + jr;
                bf16x8 v = (bf16x8){0, 0, 0, 0, 0, 0, 0, 0};
                if (j < N_) v = *(const bf16x8*)(src + (size_t)j * 1536 + dd);
                *(bf16x8*)(&vts[jr][dd]) = v;
            }
            __syncthreads();
            #pragma unroll
            for (int ps = 0; ps < 2; ++ps) {
                int idx = t + 256 * ps;
                int d = idx >> 3, ch = idx & 7;
                u16 v[8];
                #pragma unroll
                for (int k = 0; k < 8; ++k) v[k] = vts[ch * 8 + k][d];
                *(bf16x8*)(dst + (size_t)d * VTP + j0 + ch * 8) = *(bf16x8*)v;
            }
        }
    } else {
        const int i = bx - B_ * H_;
        const int h = i / PPAD, p = i % PPAD;
        for (int j = t; j < BIAS_N; j += 256) {
            float v = 0.f;
            if (p < P_ && j < N_) {
                int jm;
                if (j == 0) jm = 0;
                else { jm = j - 1; if (jm >= 196) jm -= 196; jm += 1; }
                int bucket = rp_bucket[p * P_ + jm];
                v = lk[(h * P_ + p) * 8 + bucket] * 1.44269504f;
            }
            biasT2[((size_t)h * PPAD + p) * BIAS_N + j] = v;
        }
    }
}

// ---------------------------------------------------------------------------
// attention v6: flash-style single pass, swapped MFMA operands.
// Per nt tile: QK^T (S[j][p]) -> exp (lane-local sum) -> P-tile LDS [p][j]
// -> PV (O[d][p]) accumulate. LDS 33KB (kk[2]+vv+pp), 2 barriers/nt,
// 4 blocks/CU. Softmax: no max-sub (scores bounded), deferred rinv.
// ---------------------------------------------------------------------------
__global__ __launch_bounds__(256, 4) void attn_flash(
    const u16* __restrict__ qh, const u16* __restrict__ KV,
    const u16* __restrict__ Vt, const float* __restrict__ biasT2,
    u16* __restrict__ Obuf)
{
    __shared__ __align__(16) u16 kk[2][64 * 64];   // 16 KB: K tiles (swizzled)
    __shared__ __align__(16) u16 vv[64 * 64];      //  8 KB: V tile (swizzled)
    __shared__ __align__(16) u16 pp[64 * PPITCH];  //  8.75 KB: P [p][j], pitch 70

    const int id = blockIdx.x;
    const int work = (id & 7) * 384 + (id >> 3);
    const int ptile = work & 3;
    const int rest = work >> 2;
    const int h = rest % 12;
    const int b = rest / 12;
    const int p0 = ptile * 64;

    const int t = threadIdx.x, w = t >> 6, l = t & 63;
    const int l15 = l & 15, lg = l >> 4;
    const int p0w = p0 + w * 16;
    const int rowp = w * 16 + l15;          // this lane's p row within tile

    int srow[2], sslot[2], swoff[2];
    #pragma unroll
    for (int i = 0; i < 2; ++i) {
        int c = t + 256 * i;
        srow[i] = c >> 3; sslot[i] = c & 7;
        swoff[i] = srow[i] * 64 + ((sslot[i] ^ (srow[i] & 7)) << 3);
    }

    int prow = p0w + l15; if (prow > P_ - 1) prow = P_ - 1;
    const u16* qp = qh + (size_t)prow * C_ + h * HD_ + lg * 8;
    bf16x8 qf0 = *(const bf16x8*)(qp);
    bf16x8 qf1 = *(const bf16x8*)(qp + 32);

    const u16* Kbase = KV + (size_t)b * (N_ * 1536) + h * HD_;
    const u16* Vbase = Vt + (size_t)(b * H_ + h) * (HD_ * VTP);
    const int pcl = (p0 + rowp) > (PPAD - 1) ? (PPAD - 1) : (p0 + rowp);
    const float* bias_row = biasT2 + ((size_t)h * PPAD + pcl) * BIAS_N;

    // prologue: K[0] -> kk[0]; V[0] -> regs
    bf16x8 raK[2], raV[2];
    #pragma unroll
    for (int i = 0; i < 2; ++i)
        raK[i] = *(const bf16x8*)(Kbase + (size_t)srow[i] * 1536 + sslot[i] * 8);
    #pragma unroll
    for (int i = 0; i < 2; ++i) *(bf16x8*)(&kk[0][swoff[i]]) = raK[i];
    #pragma unroll
    for (int i = 0; i < 2; ++i)
        raV[i] = *(const bf16x8*)(Vbase + (size_t)srow[i] * VTP + sslot[i] * 8);
    __syncthreads();

    float s_acc = 0.f;
    f32x4 o[4];
    #pragma unroll
    for (int i = 0; i < 4; ++i) o[i] = (f32x4){0.f, 0.f, 0.f, 0.f};

    #pragma unroll
    for (int nt = 0; nt < 7; ++nt) {
        const u16* kcur = kk[nt & 1];

        // ---- QK^T (swapped): S[j=sub*16+lg*4+rr][p=p0w+l15] ----
        f32x4 accs[4];
        #pragma unroll
        for (int i = 0; i < 4; ++i) accs[i] = (f32x4){0.f, 0.f, 0.f, 0.f};
        __builtin_amdgcn_s_setprio(1);
        #pragma unroll
        for (int kc = 0; kc < 2; ++kc)
            #pragma unroll
            for (int sub = 0; sub < 4; ++sub) {
                int row = sub * 16 + l15;
                bf16x8 kb = *(const bf16x8*)(kcur + row * 64 + (((kc * 4 + lg) ^ (row & 7)) << 3));
                accs[sub] = __builtin_amdgcn_mfma_f32_16x16x32_bf16(
                    kb, kc ? qf1 : qf0, accs[sub], 0, 0, 0);
            }
        __builtin_amdgcn_s_setprio(0);

        // ---- write V[nt] -> vv; issue K[nt+1] loads ----
        #pragma unroll
        for (int i = 0; i < 2; ++i) *(bf16x8*)(&vv[swoff[i]]) = raV[i];
        if (nt < 6) {
            #pragma unroll
            for (int i = 0; i < 2; ++i) {
                int rn = (nt + 1) * 64 + srow[i]; if (rn > N_ - 1) rn = N_ - 1;
                raK[i] = *(const bf16x8*)(Kbase + (size_t)rn * 1536 + sslot[i] * 8);
            }
        }

        // ---- bias + exp + local sum; P (unnormalized) -> pp[p][j] ----
        #pragma unroll
        for (int sub = 0; sub < 4; ++sub) {
            int jb = nt * 64 + sub * 16 + lg * 4;
            float4 b4 = *(const float4*)(bias_row + jb);
            float bb[4] = {b4.x, b4.y, b4.z, b4.w};
            float e[4];
            #pragma unroll
            for (int rr = 0; rr < 4; ++rr) {
                float ev = exp2_fast(fmaf(accs[sub][rr], SCALE_L2E, bb[rr]));
                e[rr] = (jb + rr < N_) ? ev : 0.f;
                s_acc += e[rr];
            }
            unsigned pk01 = cvt_pk_bf16(e[0], e[1]);
            unsigned pk23 = cvt_pk_bf16(e[2], e[3]);
            *(unsigned*)(&pp[rowp * PPITCH + sub * 16 + lg * 4]) = pk01;
            *(unsigned*)(&pp[rowp * PPITCH + sub * 16 + lg * 4 + 2]) = pk23;
        }
        __syncthreads();   // barrier1: vv + pp visible; kk[nt&1] reads done

        // ---- PV (swapped): O[d=dsub*16+lg*4+rr][p=l15] ----
        const int kcmax = (nt == 6) ? 1 : 2;
        __builtin_amdgcn_s_setprio(1);
        #pragma unroll
        for (int kc = 0; kc < kcmax; ++kc) {
            bf16x8 pa = *(const bf16x8*)(&pp[rowp * PPITCH + kc * 32 + lg * 8]);
            #pragma unroll
            for (int dsub = 0; dsub < 4; ++dsub) {
                int row = dsub * 16 + l15;
                bf16x8 vb = *(const bf16x8*)(vv + row * 64 + (((kc * 4 + lg) ^ (row & 7)) << 3));
                o[dsub] = __builtin_amdgcn_mfma_f32_16x16x32_bf16(vb, pa, o[dsub], 0, 0, 0);
            }
        }
        __builtin_amdgcn_s_setprio(0);

        // ---- write K[nt+1] -> kk[(nt+1)&1]; issue V[nt+1] loads ----
        if (nt < 6) {
            #pragma unroll
            for (int i = 0; i < 2; ++i) *(bf16x8*)(&kk[(nt + 1) & 1][swoff[i]]) = raK[i];
            #pragma unroll
            for (int i = 0; i < 2; ++i)
                raV[i] = *(const bf16x8*)(Vbase + (size_t)srow[i] * VTP + (nt + 1) * 64 + sslot[i] * 8);
        }
        __syncthreads();   // barrier2: PV done (vv/pp free); K[nt+1] visible
    }

    // ---- epilogue: reduce sum across lane groups, normalize, store ----
    s_acc += __shfl_xor(s_acc, 16);
    s_acc += __shfl_xor(s_acc, 32);
    float rinv = 1.0f / s_acc;

    int p = p0 + rowp;
    if (p < P_) {
        #pragma unroll
        for (int dsub = 0; dsub < 4; ++dsub) {
            u16 v4[4];
            #pragma unroll
            for (int rr = 0; rr < 4; ++rr) v4[rr] = f2bf(o[dsub][rr] * rinv);
            *(uint2*)(Obuf + ((size_t)b * P_ + p) * C_ + h * HD_ + dsub * 16 + lg * 4) =
                *(uint2*)v4;
        }
    }
}

// ---------------------------------------------------------------------------
extern "C" void kernel_launch(void* const* d_in, const int* in_sizes, int n_in,
                              void* d_out, int out_size, void* d_ws, size_t ws_size,
                              hipStream_t stream)
{
    const float* x         = (const float*)d_in[0];
    const float* q_learned = (const float*)d_in[1];
    const float* pos_embed = (const float*)d_in[2];
    const float* wk        = (const float*)d_in[3];
    const float* wv        = (const float*)d_in[4];
    const float* rpe_w     = (const float*)d_in[5];
    const float* proj_w    = (const float*)d_in[6];
    const float* proj_b    = (const float*)d_in[7];
    const int*   rp_bucket = (const int*)d_in[8];
    float* out = (float*)d_out;

    char* ws = (char*)d_ws;
    u16*   xh    = (u16*)(ws);                        // 38,633,472 B
    u16*   wkvh  = (u16*)(ws + 38633472);             //  2,359,296 B
    u16*   pwh   = (u16*)(ws + 40992768);             //  1,179,648 B
    u16*   qh    = (u16*)(ws + 42172416);             //    302,592 B
    float* lk    = (float*)(ws + 42475008);           //     75,776 B
    float* biasT2= (float*)(ws + 42550784);           //  4,153,344 B
    u16*   KV    = (u16*)(ws + 46704128);             // 77,266,944 B
    u16*   Vt    = (u16*)(ws + 123971072);            // 44,040,192 B
    u16*   Obuf  = (u16*)(ws + 168011264);            // 19,365,888 B (end ~179 MB)

    // launch 1: conversions + prep1  (20592 + 197 blocks)
    conv_prep1<<<20789, 256, 0, stream>>>(x, wk, wv, proj_w,
                                          q_learned, pos_embed, rpe_w,
                                          xh, wkvh, pwh, qh, lk);

    // launch 2: KV GEMM
    dim3 gkv(1536 / 128, (M_KV + 127) / 128);   // 12 x 197
    gemm_bf16<false><<<gkv, 256, 0, stream>>>(xh, wkvh, KV, nullptr, nullptr, M_KV, 1536);

    // launch 3: V transpose + prep2  (768 + 2496 blocks)
    vtrans_prep2<<<3264, 256, 0, stream>>>(KV, Vt, lk, rp_bucket, biasT2);

    // launch 4: attention (flash, swapped operands)
    attn_flash<<<3072, 256, 0, stream>>>(qh, KV, Vt, biasT2, Obuf);

    // launch 5: output projection
    dim3 gpr(768 / 128, (M_PR + 127) / 128);    // 6 x 99
    gemm_bf16<true><<<gpr, 256, 0, stream>>>(Obuf, pwh, nullptr, out, proj_b, M_PR, 768);
}